// Round 13
// baseline (122.801 us; speedup 1.0000x reference)
//
#include <hip/hip_runtime.h>

#define NIMG 64
#define CH 3
#define WW 64
#define PLANE 4096           // 64*64
#define IMGSZ (CH * PLANE)   // 12288
#define HO 58                // 64 - 7 + 1
#define WO 58
#define NSLOT 64             // atomic spread slots per combination
#define HS 68                // Hs row stride (floats): 272B, 16B-aligned, bank-skewed

// Block = one image pair. R13: pass A+B fused in registers.
// Thread owns 16 contiguous cols of one row: r = tid>>2, s = tid&3
// (cols 16s..16s+15). Lane order = (r%16)*4 + s, so segment s+1 is lane+1:
// the 6-col horizontal overlap d[16..21] comes from __shfl_down(d[m],1).
// All 24 float4 global loads issue in ONE phase (max MLP), horizontal 7-sum
// is a pure-VALU register slide, h[0..15] written straight to LDS Hs.
// Deletes the D buffer (LDS 35->17.7 KB), one barrier, and ~2K LDS b128
// ops/block vs R12. Pass C (vertical slide + exp) unchanged.
__global__ __launch_bounds__(256) void patchmmd_pair_kernel(
    const float* __restrict__ x, const float* __restrict__ y,
    double* __restrict__ acc)
{
    const int i = blockIdx.x, j = blockIdx.y, z = blockIdx.z;
    if (z < 2 && i >= j) return;             // symmetric combos: upper triangle

    const float* __restrict__ A = ((z == 1) ? y : x) + (size_t)i * IMGSZ;
    const float* __restrict__ B = ((z == 0) ? x : y) + (size_t)j * IMGSZ;

    __shared__ __align__(16) float Hs[64 * HS + 16];  // +16: pass-C col pad
    __shared__ float wsum[4];

    const int tid = threadIdx.x;

    // ---- Fused pass A+B ----
    {
        const int r = tid >> 2;              // row 0..63
        const int s = tid & 3;               // 16-col segment
        const int c0 = s * 16;
        const int base = r * WW + c0;

        float4 qa[6], qb[6];                 // 4 quads x {a,b} x 3 ch interleaved
        #pragma unroll
        for (int ch = 0; ch < CH; ++ch) {
            #pragma unroll
            for (int q = 0; q < 2; ++q) {    // issue in pairs to bound live set
                qa[ch * 2 + q] = *reinterpret_cast<const float4*>(A + ch * PLANE + base + q * 8);
                qb[ch * 2 + q] = *reinterpret_cast<const float4*>(B + ch * PLANE + base + q * 8);
            }
        }
        // quads at +0,+8 loaded above; +4,+12 now (keeps <=24 outstanding)
        float4 qa2[6], qb2[6];
        #pragma unroll
        for (int ch = 0; ch < CH; ++ch) {
            #pragma unroll
            for (int q = 0; q < 2; ++q) {
                qa2[ch * 2 + q] = *reinterpret_cast<const float4*>(A + ch * PLANE + base + 4 + q * 8);
                qb2[ch * 2 + q] = *reinterpret_cast<const float4*>(B + ch * PLANE + base + 4 + q * 8);
            }
        }

        float d[16];
        #pragma unroll
        for (int k = 0; k < 16; ++k) d[k] = 0.f;
        #pragma unroll
        for (int ch = 0; ch < CH; ++ch) {
            #pragma unroll
            for (int q = 0; q < 2; ++q) {
                const float4 av = qa[ch * 2 + q],  bv = qb[ch * 2 + q];   // cols q*8+0..3
                const float4 aw = qa2[ch * 2 + q], bw = qb2[ch * 2 + q];  // cols q*8+4..7
                float e;
                e = av.x - bv.x; d[q * 8 + 0] = fmaf(e, e, d[q * 8 + 0]);
                e = av.y - bv.y; d[q * 8 + 1] = fmaf(e, e, d[q * 8 + 1]);
                e = av.z - bv.z; d[q * 8 + 2] = fmaf(e, e, d[q * 8 + 2]);
                e = av.w - bv.w; d[q * 8 + 3] = fmaf(e, e, d[q * 8 + 3]);
                e = aw.x - bw.x; d[q * 8 + 4] = fmaf(e, e, d[q * 8 + 4]);
                e = aw.y - bw.y; d[q * 8 + 5] = fmaf(e, e, d[q * 8 + 5]);
                e = aw.z - bw.z; d[q * 8 + 6] = fmaf(e, e, d[q * 8 + 6]);
                e = aw.w - bw.w; d[q * 8 + 7] = fmaf(e, e, d[q * 8 + 7]);
            }
        }

        // overlap cols 16..21 from lane+1 (segment s+1 of same row).
        // s=3 pulls garbage from (r+1,s=0) but its h[10..15] -> cols 58..63,
        // which pass C discards (c < 58 guard). Values are finite.
        float dn[6];
        #pragma unroll
        for (int m = 0; m < 6; ++m) dn[m] = __shfl_down(d[m], 1, 64);

        float h[16];
        h[0] = d[0] + d[1] + d[2] + d[3] + d[4] + d[5] + d[6];
        #pragma unroll
        for (int k = 1; k < 10; ++k)  h[k] = h[k - 1] + d[k + 6]      - d[k - 1];
        #pragma unroll
        for (int k = 10; k < 16; ++k) h[k] = h[k - 1] + dn[k - 10]    - d[k - 1];

        float* dst = &Hs[r * HS + c0];
        *reinterpret_cast<float4*>(dst)      = make_float4(h[0],  h[1],  h[2],  h[3]);
        *reinterpret_cast<float4*>(dst + 4)  = make_float4(h[4],  h[5],  h[6],  h[7]);
        *reinterpret_cast<float4*>(dst + 8)  = make_float4(h[8],  h[9],  h[10], h[11]);
        *reinterpret_cast<float4*>(dst + 12) = make_float4(h[12], h[13], h[14], h[15]);
    }
    __syncthreads();

    // ---- Pass C: vertical 7-sum + exp, 8-row column segments ----
    const float NEG_INV_2S2 = -1.0f / 288.0f;   // -1/(2*sigma^2), sigma=12
    float local = 0.f;
    #pragma unroll
    for (int t = 0; t < 2; ++t) {
        const int v = tid + t * 256;         // 0..511
        const int c = v & 63;                // column (valid < 58)
        const int g = v >> 6;                // row segment: outputs rows 8g..8g+7
        float hr[14];
        #pragma unroll
        for (int k = 0; k < 14; ++k) {
            const int rk = min(8 * g + k, 63);    // clamp: g=7 needs rows 56..63 only
            hr[k] = Hs[rk * HS + c];              // 14 independent b32 reads
        }
        float V = hr[0]+hr[1]+hr[2]+hr[3]+hr[4]+hr[5]+hr[6];
        #pragma unroll
        for (int jj = 0; jj < 8; ++jj) {
            if (jj > 0) V += hr[jj + 6] - hr[jj - 1];
            if ((8 * g + jj) < HO && c < WO)
                local += __expf(V * NEG_INV_2S2);
        }
    }

    // ---- Block reduction ----
    #pragma unroll
    for (int off = 32; off; off >>= 1)
        local += __shfl_down(local, off, 64);
    if ((tid & 63) == 0) wsum[tid >> 6] = local;
    __syncthreads();
    if (tid == 0) {
        const float tot = wsum[0] + wsum[1] + wsum[2] + wsum[3];
        const int slot = z * NSLOT + ((i ^ (j * 19)) & (NSLOT - 1));
        atomicAdd(&acc[slot], (double)tot);
    }
}

// acc[z*64..]: partial sums of exp over all outputs of combination z.
// 64 threads: lane k sums slot k of each z, wave-reduce, lane 0 combines.
__global__ void patchmmd_combine_kernel(const double* __restrict__ acc,
                                        float* __restrict__ out)
{
    const int lane = threadIdx.x;
    double s0 = acc[0 * NSLOT + lane];
    double s1 = acc[1 * NSLOT + lane];
    double s2 = acc[2 * NSLOT + lane];
    #pragma unroll
    for (int off = 32; off; off >>= 1) {
        s0 += __shfl_down(s0, off, 64);
        s1 += __shfl_down(s1, off, 64);
        s2 += __shfl_down(s2, off, 64);
    }
    if (lane == 0) {
        const double inv_hw = 1.0 / (double)(HO * WO);
        const double mean_xx = 2.0 * s0 * inv_hw / (64.0 * 63.0);
        const double mean_yy = 2.0 * s1 * inv_hw / (64.0 * 63.0);
        const double mean_xy = s2 * inv_hw / (64.0 * 64.0);
        out[0] = (float)(mean_xx - 2.0 * mean_xy + mean_yy);
    }
}

extern "C" void kernel_launch(void* const* d_in, const int* in_sizes, int n_in,
                              void* d_out, int out_size, void* d_ws, size_t ws_size,
                              hipStream_t stream)
{
    const float* x = (const float*)d_in[0];
    const float* y = (const float*)d_in[1];
    float* out  = (float*)d_out;
    double* acc = (double*)d_ws;

    hipMemsetAsync(acc, 0, 3 * NSLOT * sizeof(double), stream);  // ws re-poisoned 0xAA

    dim3 grid(NIMG, NIMG, 3);
    patchmmd_pair_kernel<<<grid, 256, 0, stream>>>(x, y, acc);
    patchmmd_combine_kernel<<<1, 64, 0, stream>>>(acc, out);
}

// Round 14
// 121.631 us; speedup vs baseline: 1.0096x; 1.0096x over previous
//
#include <hip/hip_runtime.h>

#define NIMG 64
#define CH 3
#define WW 64
#define PLANE 4096           // 64*64
#define IMGSZ (CH * PLANE)   // 12288
#define HO 58                // 64 - 7 + 1
#define WO 58
#define NSLOT 64             // atomic spread slots per combination
#define HS 68                // Hs row stride (floats): 272B, 16B-aligned, bank-skewed

// Block = one image pair. R14 = R13 structure + __launch_bounds__(256,4).
// R13 post-mortem: compiler allocated 36 VGPR (8-waves/EU occupancy target),
// serializing the 24-float4 load burst -> VALUBusy 28%, 69.8us. The (256,4)
// bound caps at 4 waves/EU (128 VGPR), letting all 24 b128 loads stay in
// flight. LDS would allow 8 blocks/CU but VGPR will limit to ~4 — trading
// occupancy for per-wave MLP, which R12/R13 comparison shows is the right
// side of the trade on this latency-bound kernel.
__global__ __launch_bounds__(256, 4) void patchmmd_pair_kernel(
    const float* __restrict__ x, const float* __restrict__ y,
    double* __restrict__ acc)
{
    const int i = blockIdx.x, j = blockIdx.y, z = blockIdx.z;
    if (z < 2 && i >= j) return;             // symmetric combos: upper triangle

    const float* __restrict__ A = ((z == 1) ? y : x) + (size_t)i * IMGSZ;
    const float* __restrict__ B = ((z == 0) ? x : y) + (size_t)j * IMGSZ;

    __shared__ __align__(16) float Hs[64 * HS + 16];  // +16: pass-C col pad
    __shared__ float wsum[4];

    const int tid = threadIdx.x;

    // ---- Fused pass A+B: thread owns 16 cols of one row ----
    {
        const int r = tid >> 2;              // row 0..63
        const int s = tid & 3;               // 16-col segment
        const int c0 = s * 16;
        const int base = r * WW + c0;

        // One flat burst: 24 independent float4 loads (A,B x 3ch x 4 quads).
        float4 qa[12], qb[12];
        #pragma unroll
        for (int ch = 0; ch < CH; ++ch) {
            #pragma unroll
            for (int q = 0; q < 4; ++q) {
                qa[ch * 4 + q] = *reinterpret_cast<const float4*>(A + ch * PLANE + base + q * 4);
                qb[ch * 4 + q] = *reinterpret_cast<const float4*>(B + ch * PLANE + base + q * 4);
            }
        }

        float d[16];
        #pragma unroll
        for (int k = 0; k < 16; ++k) d[k] = 0.f;
        #pragma unroll
        for (int ch = 0; ch < CH; ++ch) {
            #pragma unroll
            for (int q = 0; q < 4; ++q) {
                const float4 av = qa[ch * 4 + q], bv = qb[ch * 4 + q];
                float e;
                e = av.x - bv.x; d[q * 4 + 0] = fmaf(e, e, d[q * 4 + 0]);
                e = av.y - bv.y; d[q * 4 + 1] = fmaf(e, e, d[q * 4 + 1]);
                e = av.z - bv.z; d[q * 4 + 2] = fmaf(e, e, d[q * 4 + 2]);
                e = av.w - bv.w; d[q * 4 + 3] = fmaf(e, e, d[q * 4 + 3]);
            }
        }

        // overlap cols 16..21 from lane+1 (segment s+1 of same row).
        // s=3 pulls garbage from (r+1,s=0) but its h[10..15] -> cols 58..63,
        // which pass C discards (c < 58 guard). Values are finite.
        float dn[6];
        #pragma unroll
        for (int m = 0; m < 6; ++m) dn[m] = __shfl_down(d[m], 1, 64);

        float h[16];
        h[0] = d[0] + d[1] + d[2] + d[3] + d[4] + d[5] + d[6];
        #pragma unroll
        for (int k = 1; k < 10; ++k)  h[k] = h[k - 1] + d[k + 6]   - d[k - 1];
        #pragma unroll
        for (int k = 10; k < 16; ++k) h[k] = h[k - 1] + dn[k - 10] - d[k - 1];

        float* dst = &Hs[r * HS + c0];
        *reinterpret_cast<float4*>(dst)      = make_float4(h[0],  h[1],  h[2],  h[3]);
        *reinterpret_cast<float4*>(dst + 4)  = make_float4(h[4],  h[5],  h[6],  h[7]);
        *reinterpret_cast<float4*>(dst + 8)  = make_float4(h[8],  h[9],  h[10], h[11]);
        *reinterpret_cast<float4*>(dst + 12) = make_float4(h[12], h[13], h[14], h[15]);
    }
    __syncthreads();

    // ---- Pass C: vertical 7-sum + exp, 8-row column segments ----
    const float NEG_INV_2S2 = -1.0f / 288.0f;   // -1/(2*sigma^2), sigma=12
    float local = 0.f;
    #pragma unroll
    for (int t = 0; t < 2; ++t) {
        const int v = tid + t * 256;         // 0..511
        const int c = v & 63;                // column (valid < 58)
        const int g = v >> 6;                // row segment: outputs rows 8g..8g+7
        float hr[14];
        #pragma unroll
        for (int k = 0; k < 14; ++k) {
            const int rk = min(8 * g + k, 63);    // clamp: g=7 needs rows 56..63 only
            hr[k] = Hs[rk * HS + c];              // 14 independent b32 reads
        }
        float V = hr[0]+hr[1]+hr[2]+hr[3]+hr[4]+hr[5]+hr[6];
        #pragma unroll
        for (int jj = 0; jj < 8; ++jj) {
            if (jj > 0) V += hr[jj + 6] - hr[jj - 1];
            if ((8 * g + jj) < HO && c < WO)
                local += __expf(V * NEG_INV_2S2);
        }
    }

    // ---- Block reduction ----
    #pragma unroll
    for (int off = 32; off; off >>= 1)
        local += __shfl_down(local, off, 64);
    if ((tid & 63) == 0) wsum[tid >> 6] = local;
    __syncthreads();
    if (tid == 0) {
        const float tot = wsum[0] + wsum[1] + wsum[2] + wsum[3];
        const int slot = z * NSLOT + ((i ^ (j * 19)) & (NSLOT - 1));
        atomicAdd(&acc[slot], (double)tot);
    }
}

// acc[z*64..]: partial sums of exp over all outputs of combination z.
// 64 threads: lane k sums slot k of each z, wave-reduce, lane 0 combines.
__global__ void patchmmd_combine_kernel(const double* __restrict__ acc,
                                        float* __restrict__ out)
{
    const int lane = threadIdx.x;
    double s0 = acc[0 * NSLOT + lane];
    double s1 = acc[1 * NSLOT + lane];
    double s2 = acc[2 * NSLOT + lane];
    #pragma unroll
    for (int off = 32; off; off >>= 1) {
        s0 += __shfl_down(s0, off, 64);
        s1 += __shfl_down(s1, off, 64);
        s2 += __shfl_down(s2, off, 64);
    }
    if (lane == 0) {
        const double inv_hw = 1.0 / (double)(HO * WO);
        const double mean_xx = 2.0 * s0 * inv_hw / (64.0 * 63.0);
        const double mean_yy = 2.0 * s1 * inv_hw / (64.0 * 63.0);
        const double mean_xy = s2 * inv_hw / (64.0 * 64.0);
        out[0] = (float)(mean_xx - 2.0 * mean_xy + mean_yy);
    }
}

extern "C" void kernel_launch(void* const* d_in, const int* in_sizes, int n_in,
                              void* d_out, int out_size, void* d_ws, size_t ws_size,
                              hipStream_t stream)
{
    const float* x = (const float*)d_in[0];
    const float* y = (const float*)d_in[1];
    float* out  = (float*)d_out;
    double* acc = (double*)d_ws;

    hipMemsetAsync(acc, 0, 3 * NSLOT * sizeof(double), stream);  // ws re-poisoned 0xAA

    dim3 grid(NIMG, NIMG, 3);
    patchmmd_pair_kernel<<<grid, 256, 0, stream>>>(x, y, acc);
    patchmmd_combine_kernel<<<1, 64, 0, stream>>>(acc, out);
}

// Round 15
// 94.036 us; speedup vs baseline: 1.3059x; 1.2935x over previous
//
#include <hip/hip_runtime.h>

#define NIMG 64
#define CH 3
#define WW 64
#define PLANE 4096           // 64*64
#define IMGSZ (CH * PLANE)   // 12288
#define HO 58                // 64 - 7 + 1
#define WO 58
#define NSLOT 64             // atomic spread slots per combination
#define LS 68                // single shared-buffer row stride (floats)

// Block = one image pair. R15 = R12 structure with Hs computed IN PLACE over
// D: pass B reads its 14 D values into registers (3xb128+1xb64, 2-way banks
// = free), barrier, overwrites the same row span with h. Halves LDS
// (35->17.5 KB) -> 8 blocks/CU = 32 waves/CU (the cap), doubling latency-
// hiding TLP, at the cost of one extra barrier. Pass A & C unchanged from
// R12 (R13/R14 lesson: compiler won't hold large global-load bursts in
// registers; keep MLP in small proven iterations).
__global__ __launch_bounds__(256) void patchmmd_pair_kernel(
    const float* __restrict__ x, const float* __restrict__ y,
    double* __restrict__ acc)
{
    const int i = blockIdx.x, j = blockIdx.y, z = blockIdx.z;
    if (z < 2 && i >= j) return;             // symmetric combos: upper triangle

    const float* __restrict__ A = ((z == 1) ? y : x) + (size_t)i * IMGSZ;
    const float* __restrict__ B = ((z == 0) ? x : y) + (size_t)j * IMGSZ;

    __shared__ __align__(16) float S[64 * LS + 16];  // D, then Hs in place
    __shared__ float wsum[4];

    const int tid = threadIdx.x;

    // ---- Pass A: D[r][c] = sum_ch (a-b)^2 -> S ----
    #pragma unroll
    for (int t = 0; t < 4; ++t) {
        const int v = tid + t * 256;         // quad id 0..1023
        const int r = v >> 4, q = v & 15;
        const int off = r * WW + q * 4;
        float4 d = make_float4(0.f, 0.f, 0.f, 0.f);
        #pragma unroll
        for (int ch = 0; ch < CH; ++ch) {
            const float4 av = *reinterpret_cast<const float4*>(A + ch * PLANE + off);
            const float4 bv = *reinterpret_cast<const float4*>(B + ch * PLANE + off);
            const float ex = av.x - bv.x, ey = av.y - bv.y,
                        ez = av.z - bv.z, ew = av.w - bv.w;
            d.x = fmaf(ex, ex, d.x); d.y = fmaf(ey, ey, d.y);
            d.z = fmaf(ez, ez, d.z); d.w = fmaf(ew, ew, d.w);
        }
        *reinterpret_cast<float4*>(&S[r * LS + q * 4]) = d;
    }
    __syncthreads();

    // ---- Pass B read: D[r][8s..8s+13] -> regs (2 items/thread) ----
    // s=7 reads into row pad / next row's D (valid-but-unrelated data, read
    // BEFORE any overwrite): contaminates only h for cols 58..63, which pass
    // C discards via the c<WO guard.
    float dv[2][14];
    #pragma unroll
    for (int t = 0; t < 2; ++t) {
        const int v = tid + t * 256;         // 0..511
        const int r = v >> 3, s = v & 7;     // row, 8-col segment
        const float* src = &S[r * LS + s * 8];
        const float4 a0 = *reinterpret_cast<const float4*>(src);
        const float4 a1 = *reinterpret_cast<const float4*>(src + 4);
        const float4 a2 = *reinterpret_cast<const float4*>(src + 8);
        const float2 a3 = *reinterpret_cast<const float2*>(src + 12);
        dv[t][0]=a0.x; dv[t][1]=a0.y; dv[t][2]=a0.z; dv[t][3]=a0.w;
        dv[t][4]=a1.x; dv[t][5]=a1.y; dv[t][6]=a1.z; dv[t][7]=a1.w;
        dv[t][8]=a2.x; dv[t][9]=a2.y; dv[t][10]=a2.z; dv[t][11]=a2.w;
        dv[t][12]=a3.x; dv[t][13]=a3.y;
    }
    __syncthreads();                         // all D reads done before overwrite

    // ---- Pass B write: h = horizontal 7-sum, in place over D ----
    #pragma unroll
    for (int t = 0; t < 2; ++t) {
        const int v = tid + t * 256;
        const int r = v >> 3, s = v & 7;
        float h[8];
        h[0] = dv[t][0]+dv[t][1]+dv[t][2]+dv[t][3]+dv[t][4]+dv[t][5]+dv[t][6];
        #pragma unroll
        for (int k = 1; k < 8; ++k)
            h[k] = h[k - 1] + dv[t][k + 6] - dv[t][k - 1];
        float* dst = &S[r * LS + s * 8];
        *reinterpret_cast<float4*>(dst)     = make_float4(h[0], h[1], h[2], h[3]);
        *reinterpret_cast<float4*>(dst + 4) = make_float4(h[4], h[5], h[6], h[7]);
    }
    __syncthreads();

    // ---- Pass C: vertical 7-sum + exp, 8-row column segments ----
    const float NEG_INV_2S2 = -1.0f / 288.0f;   // -1/(2*sigma^2), sigma=12
    float local = 0.f;
    #pragma unroll
    for (int t = 0; t < 2; ++t) {
        const int v = tid + t * 256;         // 0..511
        const int c = v & 63;                // column (valid < 58)
        const int g = v >> 6;                // row segment: outputs rows 8g..8g+7
        float hr[14];
        #pragma unroll
        for (int k = 0; k < 14; ++k) {
            const int rk = min(8 * g + k, 63);    // clamp: g=7 needs rows 56..63 only
            hr[k] = S[rk * LS + c];               // 14 independent b32 reads
        }
        float V = hr[0]+hr[1]+hr[2]+hr[3]+hr[4]+hr[5]+hr[6];
        #pragma unroll
        for (int jj = 0; jj < 8; ++jj) {
            if (jj > 0) V += hr[jj + 6] - hr[jj - 1];
            if ((8 * g + jj) < HO && c < WO)
                local += __expf(V * NEG_INV_2S2);
        }
    }

    // ---- Block reduction ----
    #pragma unroll
    for (int off = 32; off; off >>= 1)
        local += __shfl_down(local, off, 64);
    if ((tid & 63) == 0) wsum[tid >> 6] = local;
    __syncthreads();
    if (tid == 0) {
        const float tot = wsum[0] + wsum[1] + wsum[2] + wsum[3];
        const int slot = z * NSLOT + ((i ^ (j * 19)) & (NSLOT - 1));
        atomicAdd(&acc[slot], (double)tot);
    }
}

// acc[z*64..]: partial sums of exp over all outputs of combination z.
// 64 threads: lane k sums slot k of each z, wave-reduce, lane 0 combines.
__global__ void patchmmd_combine_kernel(const double* __restrict__ acc,
                                        float* __restrict__ out)
{
    const int lane = threadIdx.x;
    double s0 = acc[0 * NSLOT + lane];
    double s1 = acc[1 * NSLOT + lane];
    double s2 = acc[2 * NSLOT + lane];
    #pragma unroll
    for (int off = 32; off; off >>= 1) {
        s0 += __shfl_down(s0, off, 64);
        s1 += __shfl_down(s1, off, 64);
        s2 += __shfl_down(s2, off, 64);
    }
    if (lane == 0) {
        const double inv_hw = 1.0 / (double)(HO * WO);
        const double mean_xx = 2.0 * s0 * inv_hw / (64.0 * 63.0);
        const double mean_yy = 2.0 * s1 * inv_hw / (64.0 * 63.0);
        const double mean_xy = s2 * inv_hw / (64.0 * 64.0);
        out[0] = (float)(mean_xx - 2.0 * mean_xy + mean_yy);
    }
}

extern "C" void kernel_launch(void* const* d_in, const int* in_sizes, int n_in,
                              void* d_out, int out_size, void* d_ws, size_t ws_size,
                              hipStream_t stream)
{
    const float* x = (const float*)d_in[0];
    const float* y = (const float*)d_in[1];
    float* out  = (float*)d_out;
    double* acc = (double*)d_ws;

    hipMemsetAsync(acc, 0, 3 * NSLOT * sizeof(double), stream);  // ws re-poisoned 0xAA

    dim3 grid(NIMG, NIMG, 3);
    patchmmd_pair_kernel<<<grid, 256, 0, stream>>>(x, y, acc);
    patchmmd_combine_kernel<<<1, 64, 0, stream>>>(acc, out);
}